// Round 1
// baseline (230.451 us; speedup 1.0000x reference)
//
#include <hip/hip_runtime.h>
#include <hip/hip_bf16.h>

// NonlocalBlock: B=4, C=64, H=W=96 (N=9216), Ci=32, COMPRESSION=2 (M=4608).
// Plan:
//  k1: projections theta/phi/g via bf16 MFMA (16x16x32), pooling fused via
//      register pairs (C-layout rows = 4q+r). Outputs bf16: theta[B][N][32],
//      phi[B][M][32], gT[B][32][M] (transposed for contiguous V fragments).
//  k2: flash attention, max-free softmax (exp2 in f32; logits bounded ~35 so
//      no overflow), P through per-wave LDS (C->A layout transform), PV MFMA,
//      fused output projection (y @ w_out^T + b_out + x) in the epilogue.

#define NQ 9216
#define MM 4608
#define LOG2E 1.44269504088896340736f

typedef __attribute__((ext_vector_type(8))) short bf16x8;   // 8 bf16, 4 VGPRs
typedef __attribute__((ext_vector_type(4))) float f32x4;    // MFMA C/D

static __device__ __forceinline__ unsigned short f2bf(float f) {
    unsigned u = __float_as_uint(f);
    unsigned r = (u + 0x7fffu + ((u >> 16) & 1u)) >> 16;   // RNE
    return (unsigned short)r;
}

// ---------------------------------------------------------------------------
// Kernel 1: projections. Grid: 288 blocks x 256 thr (4 waves, 2 n-tiles/wave).
// Each 16-row n-tile: A-frags from x (f32->bf16), 12 MFMA (3 proj x 2 ct x 2 k).
// ---------------------------------------------------------------------------
__global__ __launch_bounds__(256) void proj_kernel(
    const float* __restrict__ x,
    const float* __restrict__ wt, const float* __restrict__ bt,
    const float* __restrict__ wp, const float* __restrict__ bp,
    const float* __restrict__ wg, const float* __restrict__ bg,
    unsigned short* __restrict__ theta, unsigned short* __restrict__ phi,
    unsigned short* __restrict__ gT)
{
    const int lane = threadIdx.x & 63;
    const int wid  = threadIdx.x >> 6;
    const int q = lane >> 4;
    const int c = lane & 15;

    const float* Wm[3] = {wt, wp, wg};
    const float* Bm[3] = {bt, bp, bg};

    // Weight B-fragments: B[k][ci] = W[ci][k]; lane holds ci=ct*16+c, k=q*8+j.
    bf16x8 wf[3][2][2];
    float bias[3][2];
#pragma unroll
    for (int p = 0; p < 3; ++p) {
#pragma unroll
        for (int ct = 0; ct < 2; ++ct) {
            bias[p][ct] = Bm[p][ct * 16 + c];
#pragma unroll
            for (int ks = 0; ks < 2; ++ks) {
                const float* wsrc = Wm[p] + (ct * 16 + c) * 64 + ks * 32 + q * 8;
                f32x4 w0 = *(const f32x4*)wsrc;
                f32x4 w1 = *(const f32x4*)(wsrc + 4);
                unsigned short* wk = (unsigned short*)&wf[p][ct][ks];
#pragma unroll
                for (int j = 0; j < 4; ++j) { wk[j] = f2bf(w0[j]); wk[4 + j] = f2bf(w1[j]); }
            }
        }
    }

    const int wgid = blockIdx.x * 4 + wid;
#pragma unroll
    for (int it = 0; it < 2; ++it) {
        const int t  = wgid * 2 + it;          // 0..2303 n-tiles
        const int b  = t / 576;
        const int n0 = (t % 576) * 16;

        // A-frags: A[m][k] -> xf[n0+c][k] = x[b][k][n0+c]
        bf16x8 af[2];
#pragma unroll
        for (int ks = 0; ks < 2; ++ks) {
            unsigned short* ap = (unsigned short*)&af[ks];
#pragma unroll
            for (int j = 0; j < 8; ++j)
                ap[j] = f2bf(x[(b * 64 + ks * 32 + q * 8 + j) * NQ + n0 + c]);
        }

#pragma unroll
        for (int p = 0; p < 3; ++p) {
#pragma unroll
            for (int ct = 0; ct < 2; ++ct) {
                f32x4 acc = {0.f, 0.f, 0.f, 0.f};
                acc = __builtin_amdgcn_mfma_f32_16x16x32_bf16(af[0], wf[p][ct][0], acc, 0, 0, 0);
                acc = __builtin_amdgcn_mfma_f32_16x16x32_bf16(af[1], wf[p][ct][1], acc, 0, 0, 0);
#pragma unroll
                for (int r = 0; r < 4; ++r) acc[r] += bias[p][ct];
                const int ci = ct * 16 + c;
                if (p == 0) {
#pragma unroll
                    for (int r = 0; r < 4; ++r)
                        theta[(b * NQ + n0 + 4 * q + r) * 32 + ci] = f2bf(acc[r]);
                } else {
                    // max-pool spatial pairs: rows (4q+r) pair within regs
                    float v0 = fmaxf(acc[0], acc[1]);
                    float v1 = fmaxf(acc[2], acc[3]);
                    const int m0 = (n0 >> 1) + 2 * q;
                    if (p == 1) {
                        phi[(b * MM + m0) * 32 + ci]     = f2bf(v0);
                        phi[(b * MM + m0 + 1) * 32 + ci] = f2bf(v1);
                    } else {
                        gT[(b * 32 + ci) * MM + m0]     = f2bf(v0);
                        gT[(b * 32 + ci) * MM + m0 + 1] = f2bf(v1);
                    }
                }
            }
        }
    }
}

// ---------------------------------------------------------------------------
// Kernel 2: flash attention + fused out-projection.
// Grid: 576 blocks (b x 144 q-tiles of 128 rows), 128 thr = 2 waves x 32 rows.
// ---------------------------------------------------------------------------
__global__ __launch_bounds__(128) void attn_kernel(
    const unsigned short* __restrict__ theta, const unsigned short* __restrict__ phi,
    const unsigned short* __restrict__ gT, const float* __restrict__ w_out,
    const float* __restrict__ b_out, const float* __restrict__ x,
    float* __restrict__ out)
{
    __shared__ unsigned short kld[64 * 40];      // K tile, pad 32->40 (<=2-way)
    __shared__ unsigned short vld[32 * 72];      // V^T tile, pad 64->72
    __shared__ unsigned short pld[2][32 * 72];   // per-wave P / y scratch

    const int tid  = threadIdx.x;
    const int w    = tid >> 6;
    const int lane = tid & 63;
    const int q = lane >> 4;
    const int c = lane & 15;

    const int b  = blockIdx.x / 144;
    const int qb = blockIdx.x % 144;
    const int nb = qb * 64 + w * 32;   // this wave's first Q row

    // Q fragments (A layout: row=c, k=q*8+j), direct from global bf16
    bf16x8 qf[2];
#pragma unroll
    for (int rt = 0; rt < 2; ++rt)
        qf[rt] = *(const bf16x8*)(theta + (b * NQ + nb + rt * 16 + c) * 32 + q * 8);

    // w_out B-frags: B[k=ci][col=chn] = w_out[chn][ci]
    bf16x8 wof[4];
    float bo[4];
#pragma unroll
    for (int ct = 0; ct < 4; ++ct) {
        const float* wsrc = w_out + (ct * 16 + c) * 32 + q * 8;
        f32x4 w0 = *(const f32x4*)wsrc;
        f32x4 w1 = *(const f32x4*)(wsrc + 4);
        unsigned short* wk = (unsigned short*)&wof[ct];
#pragma unroll
        for (int j = 0; j < 4; ++j) { wk[j] = f2bf(w0[j]); wk[4 + j] = f2bf(w1[j]); }
        bo[ct] = b_out[ct * 16 + c];
    }

    f32x4 acc[2][2];
    f32x4 lsum[2];
#pragma unroll
    for (int rt = 0; rt < 2; ++rt) {
        lsum[rt] = (f32x4){0.f, 0.f, 0.f, 0.f};
#pragma unroll
        for (int s2 = 0; s2 < 2; ++s2) acc[rt][s2] = (f32x4){0.f, 0.f, 0.f, 0.f};
    }

    for (int mt = 0; mt < 72; ++mt) {
        __syncthreads();   // protect kld/vld reuse
#pragma unroll
        for (int rep = 0; rep < 2; ++rep) {
            const int i = rep * 128 + tid;     // 0..255
            { const int row = i >> 2, ch = i & 3;   // K: 64 rows x 4 chunks
              *(bf16x8*)(kld + row * 40 + ch * 8) =
                  *(const bf16x8*)(phi + (b * MM + mt * 64 + row) * 32 + ch * 8); }
            { const int ci = i >> 3, ch = i & 7;    // V^T: 32 rows x 8 chunks
              *(bf16x8*)(vld + ci * 72 + ch * 8) =
                  *(const bf16x8*)(gT + (b * 32 + ci) * MM + mt * 64 + ch * 8); }
        }
        __syncthreads();

        bf16x8 kf[4], vf[2][2];
#pragma unroll
        for (int ct = 0; ct < 4; ++ct)
            kf[ct] = *(const bf16x8*)(kld + (ct * 16 + c) * 40 + q * 8);
#pragma unroll
        for (int s2 = 0; s2 < 2; ++s2)
#pragma unroll
            for (int st = 0; st < 2; ++st)
                vf[s2][st] = *(const bf16x8*)(vld + (s2 * 16 + c) * 72 + st * 32 + q * 8);

        // S = Q K^T, exp2 (no max needed: |logit| <~35 -> fits f32), P -> LDS
#pragma unroll
        for (int rt = 0; rt < 2; ++rt) {
            f32x4 s[4];
#pragma unroll
            for (int ct = 0; ct < 4; ++ct) {
                f32x4 z = {0.f, 0.f, 0.f, 0.f};
                s[ct] = __builtin_amdgcn_mfma_f32_16x16x32_bf16(qf[rt], kf[ct], z, 0, 0, 0);
            }
#pragma unroll
            for (int ct = 0; ct < 4; ++ct) {
#pragma unroll
                for (int r = 0; r < 4; ++r) {
                    float p = __builtin_amdgcn_exp2f(s[ct][r] * LOG2E);
                    lsum[rt][r] += p;
                    pld[w][(rt * 16 + 4 * q + r) * 72 + ct * 16 + c] = f2bf(p);
                }
            }
        }
        // P is wave-private in pld[w]: no block barrier needed
#pragma unroll
        for (int rt = 0; rt < 2; ++rt) {
#pragma unroll
            for (int st = 0; st < 2; ++st) {
                bf16x8 pf = *(const bf16x8*)(pld[w] + (rt * 16 + c) * 72 + st * 32 + q * 8);
#pragma unroll
                for (int s2 = 0; s2 < 2; ++s2)
                    acc[rt][s2] = __builtin_amdgcn_mfma_f32_16x16x32_bf16(pf, vf[s2][st], acc[rt][s2], 0, 0, 0);
            }
        }
    }

    // row-sum reduction across the 16 lanes of each quad-group
#pragma unroll
    for (int rt = 0; rt < 2; ++rt)
#pragma unroll
        for (int m = 1; m < 16; m <<= 1)
#pragma unroll
            for (int r = 0; r < 4; ++r)
                lsum[rt][r] += __shfl_xor(lsum[rt][r], m);

    // y = acc / l  -> pld (stride 40) -> A-frags -> out-projection MFMA
#pragma unroll
    for (int rt = 0; rt < 2; ++rt) {
        f32x4 rv;
#pragma unroll
        for (int r = 0; r < 4; ++r) rv[r] = 1.0f / lsum[rt][r];
#pragma unroll
        for (int s2 = 0; s2 < 2; ++s2)
#pragma unroll
            for (int r = 0; r < 4; ++r)
                pld[w][(rt * 16 + 4 * q + r) * 40 + s2 * 16 + c] = f2bf(acc[rt][s2][r] * rv[r]);
    }
#pragma unroll
    for (int rt = 0; rt < 2; ++rt) {
        bf16x8 yf = *(const bf16x8*)(pld[w] + (rt * 16 + c) * 40 + q * 8);
#pragma unroll
        for (int ct = 0; ct < 4; ++ct) {
            f32x4 z = {0.f, 0.f, 0.f, 0.f};
            f32x4 o = __builtin_amdgcn_mfma_f32_16x16x32_bf16(yf, wof[ct], z, 0, 0, 0);
#pragma unroll
            for (int r = 0; r < 4; ++r) {
                const int n = nb + rt * 16 + 4 * q + r;
                const int addr = (b * 64 + ct * 16 + c) * NQ + n;
                out[addr] = o[r] + bo[ct] + x[addr];
            }
        }
    }
}

extern "C" void kernel_launch(void* const* d_in, const int* in_sizes, int n_in,
                              void* d_out, int out_size, void* d_ws, size_t ws_size,
                              hipStream_t stream) {
    const float* x       = (const float*)d_in[0];
    const float* w_theta = (const float*)d_in[1];
    const float* b_theta = (const float*)d_in[2];
    const float* w_phi   = (const float*)d_in[3];
    const float* b_phi   = (const float*)d_in[4];
    const float* w_g     = (const float*)d_in[5];
    const float* b_g     = (const float*)d_in[6];
    const float* w_out   = (const float*)d_in[7];
    const float* b_out   = (const float*)d_in[8];
    float* out = (float*)d_out;

    // ws: theta[4][9216][32] bf16 | phi[4][4608][32] bf16 | gT[4][32][4608] bf16
    unsigned short* theta = (unsigned short*)d_ws;
    unsigned short* phi   = theta + 4 * NQ * 32;
    unsigned short* gT    = phi + 4 * MM * 32;

    proj_kernel<<<288, 256, 0, stream>>>(x, w_theta, b_theta, w_phi, b_phi,
                                         w_g, b_g, theta, phi, gT);
    attn_kernel<<<576, 128, 0, stream>>>(theta, phi, gT, w_out, b_out, x, out);
}

// Round 2
// 160.179 us; speedup vs baseline: 1.4387x; 1.4387x over previous
//
#include <hip/hip_runtime.h>
#include <hip/hip_bf16.h>

// NonlocalBlock: B=4, C=64, H=W=96 (N=9216), Ci=32, COMPRESSION=2 (M=4608).
// R2: split-K flash attention (max-free softmax => partials just add),
//     transposed P LDS scratch (b64 writes), LOG2E folded into theta,
//     proj with 1 tile/wave + LDS-transposed coalesced gT stores,
//     separate reduce kernel doing sum/divide + out-projection + residual.

#define NQ 9216
#define MM 4608
#define LOG2E 1.44269504088896340736f

typedef __attribute__((ext_vector_type(8))) short bf16x8;   // 8 bf16, 4 VGPRs
typedef __attribute__((ext_vector_type(4))) float f32x4;    // MFMA C/D
typedef __attribute__((ext_vector_type(4))) unsigned short u16x4;

static __device__ __forceinline__ unsigned short f2bf(float f) {
    unsigned u = __float_as_uint(f);
    unsigned r = (u + 0x7fffu + ((u >> 16) & 1u)) >> 16;   // RNE
    return (unsigned short)r;
}

// ---------------------------------------------------------------------------
// Kernel 1: projections. Grid: 576 blocks x 256 thr (4 waves, 1 n-tile each;
// block covers 64 consecutive n). theta pre-scaled by LOG2E. gT staged through
// LDS so global stores are 64B-coalesced per ci row.
// ---------------------------------------------------------------------------
__global__ __launch_bounds__(256) void proj_kernel(
    const float* __restrict__ x,
    const float* __restrict__ wt, const float* __restrict__ bt,
    const float* __restrict__ wp, const float* __restrict__ bp,
    const float* __restrict__ wg, const float* __restrict__ bg,
    unsigned short* __restrict__ theta, unsigned short* __restrict__ phi,
    unsigned short* __restrict__ gT)
{
    __shared__ unsigned short gst[32 * 36];   // g block tile: [ci][m-local 32], pad 36

    const int tid  = threadIdx.x;
    const int wid  = tid >> 6;
    const int lane = tid & 63;
    const int q = lane >> 4;
    const int c = lane & 15;

    const int b     = blockIdx.x / 144;
    const int n0blk = (blockIdx.x % 144) * 64;
    const int n0    = n0blk + wid * 16;

    const float* Wm[3] = {wt, wp, wg};
    const float* Bm[3] = {bt, bp, bg};

    // Weight B-fragments: B[k][ci] = W[ci][k]; lane holds ci=ct*16+c, k=q*8+j.
    bf16x8 wf[3][2][2];
    float bias[3][2];
#pragma unroll
    for (int p = 0; p < 3; ++p) {
#pragma unroll
        for (int ct = 0; ct < 2; ++ct) {
            bias[p][ct] = Bm[p][ct * 16 + c];
#pragma unroll
            for (int ks = 0; ks < 2; ++ks) {
                const float* wsrc = Wm[p] + (ct * 16 + c) * 64 + ks * 32 + q * 8;
                f32x4 w0 = *(const f32x4*)wsrc;
                f32x4 w1 = *(const f32x4*)(wsrc + 4);
                unsigned short* wk = (unsigned short*)&wf[p][ct][ks];
#pragma unroll
                for (int j = 0; j < 4; ++j) { wk[j] = f2bf(w0[j]); wk[4 + j] = f2bf(w1[j]); }
            }
        }
    }

    // A-frags: A[m][k] -> xf[n0+c][k] = x[b][k][n0+c]
    bf16x8 af[2];
#pragma unroll
    for (int ks = 0; ks < 2; ++ks) {
        unsigned short* ap = (unsigned short*)&af[ks];
#pragma unroll
        for (int j = 0; j < 8; ++j)
            ap[j] = f2bf(x[(b * 64 + ks * 32 + q * 8 + j) * NQ + n0 + c]);
    }

#pragma unroll
    for (int p = 0; p < 3; ++p) {
#pragma unroll
        for (int ct = 0; ct < 2; ++ct) {
            f32x4 acc = {0.f, 0.f, 0.f, 0.f};
            acc = __builtin_amdgcn_mfma_f32_16x16x32_bf16(af[0], wf[p][ct][0], acc, 0, 0, 0);
            acc = __builtin_amdgcn_mfma_f32_16x16x32_bf16(af[1], wf[p][ct][1], acc, 0, 0, 0);
#pragma unroll
            for (int r = 0; r < 4; ++r) acc[r] += bias[p][ct];
            const int ci = ct * 16 + c;
            if (p == 0) {
                // theta *= LOG2E so attention can use exp2 directly
#pragma unroll
                for (int r = 0; r < 4; ++r)
                    theta[(b * NQ + n0 + 4 * q + r) * 32 + ci] = f2bf(acc[r] * LOG2E);
            } else {
                // max-pool spatial pairs: rows (4q+r) pair within regs
                float v0 = fmaxf(acc[0], acc[1]);
                float v1 = fmaxf(acc[2], acc[3]);
                if (p == 1) {
                    const int m0 = (n0 >> 1) + 2 * q;
                    phi[(b * MM + m0) * 32 + ci]     = f2bf(v0);
                    phi[(b * MM + m0 + 1) * 32 + ci] = f2bf(v1);
                } else {
                    // stage to LDS; m-local = wid*8 + 2q + {0,1}
                    unsigned short h0 = f2bf(v0), h1 = f2bf(v1);
                    *(unsigned int*)(gst + ci * 36 + wid * 8 + 2 * q) =
                        (unsigned int)h0 | ((unsigned int)h1 << 16);
                }
            }
        }
    }

    __syncthreads();
    // cooperative coalesced gT store: thread t -> ci=t>>3, 4 m's at (t&7)*4
    {
        const int t  = tid & 255;
        const int ci = t >> 3;
        const int m4 = (t & 7) * 4;
        u16x4 v = *(const u16x4*)(gst + ci * 36 + m4);
        *(u16x4*)(gT + (b * 32 + ci) * MM + (n0blk >> 1) + m4) = v;
    }
}

// ---------------------------------------------------------------------------
// Kernel 2: split-K flash attention. Grid: KS*4*72 blocks x 256 thr
// (4 waves x 32 q-rows = 128 q-rows/block). Each block handles mtpc M-tiles.
// Writes raw partial numerator (pacc f32) and denominator (plsum f32).
// ---------------------------------------------------------------------------
__global__ __launch_bounds__(256) void attn_kernel(
    const unsigned short* __restrict__ theta, const unsigned short* __restrict__ phi,
    const unsigned short* __restrict__ gT,
    float* __restrict__ pacc, float* __restrict__ plsum, int mtpc)
{
    __shared__ unsigned short kld[64 * 40];        // K tile [m-row][ci], pad 40
    __shared__ unsigned short vld[32 * 72];        // V^T tile [ci][m], pad 72
    __shared__ unsigned short pldT[4][64 * 36];    // per-wave P^T: [m][n-row], pad 36

    const int tid  = threadIdx.x;
    const int w    = tid >> 6;
    const int lane = tid & 63;
    const int q = lane >> 4;
    const int c = lane & 15;

    const int blk = blockIdx.x;
    const int ks  = blk / 288;
    const int rem = blk % 288;
    const int b   = rem / 72;
    const int qb  = rem % 72;
    const int nb  = qb * 128 + w * 32;   // this wave's first Q row

    // Q fragments (A layout: row=c, k=q*8+j), bf16, pre-scaled by LOG2E
    bf16x8 qf[2];
#pragma unroll
    for (int rt = 0; rt < 2; ++rt)
        qf[rt] = *(const bf16x8*)(theta + (b * NQ + nb + rt * 16 + c) * 32 + q * 8);

    f32x4 acc[2][2];
    f32x4 lsum[2];
#pragma unroll
    for (int rt = 0; rt < 2; ++rt) {
        lsum[rt] = (f32x4){0.f, 0.f, 0.f, 0.f};
#pragma unroll
        for (int s2 = 0; s2 < 2; ++s2) acc[rt][s2] = (f32x4){0.f, 0.f, 0.f, 0.f};
    }

    const int mt0 = ks * mtpc;
    for (int mi = 0; mi < mtpc; ++mi) {
        const int mt = mt0 + mi;
        __syncthreads();   // protect kld/vld reuse
        {   // stage: 256 threads, one K chunk + one V chunk each
            const int row = tid >> 2, chk = tid & 3;   // K: 64 rows x 4 chunks
            *(bf16x8*)(kld + row * 40 + chk * 8) =
                *(const bf16x8*)(phi + (b * MM + mt * 64 + row) * 32 + chk * 8);
            const int ci = tid >> 3, chv = tid & 7;    // V^T: 32 rows x 8 chunks
            *(bf16x8*)(vld + ci * 72 + chv * 8) =
                *(const bf16x8*)(gT + (b * 32 + ci) * MM + mt * 64 + chv * 8);
        }
        __syncthreads();

        bf16x8 kf[4], vf[2][2];
#pragma unroll
        for (int ct = 0; ct < 4; ++ct)
            kf[ct] = *(const bf16x8*)(kld + (ct * 16 + c) * 40 + q * 8);
#pragma unroll
        for (int s2 = 0; s2 < 2; ++s2)
#pragma unroll
            for (int st = 0; st < 2; ++st)
                vf[s2][st] = *(const bf16x8*)(vld + (s2 * 16 + c) * 72 + st * 32 + q * 8);

        // S = Q K^T (log2-scaled), P = exp2(S); store P^T to LDS via b64
#pragma unroll
        for (int rt = 0; rt < 2; ++rt) {
#pragma unroll
            for (int ct = 0; ct < 4; ++ct) {
                f32x4 z = {0.f, 0.f, 0.f, 0.f};
                f32x4 s = __builtin_amdgcn_mfma_f32_16x16x32_bf16(qf[rt], kf[ct], z, 0, 0, 0);
                u16x4 h;
#pragma unroll
                for (int r = 0; r < 4; ++r) {
                    float p = __builtin_amdgcn_exp2f(s[r]);
                    lsum[rt][r] += p;
                    h[r] = f2bf(p);
                }
                // P[row=rt*16+4q+r][col=ct*16+c] -> pldT[m=col][n=row]
                *(u16x4*)(pldT[w] + (ct * 16 + c) * 36 + rt * 16 + 4 * q) = h;
            }
        }
        // P^T is wave-private: no block barrier needed
#pragma unroll
        for (int rt = 0; rt < 2; ++rt) {
#pragma unroll
            for (int st = 0; st < 2; ++st) {
                bf16x8 pf;
                unsigned short* pp = (unsigned short*)&pf;
#pragma unroll
                for (int j = 0; j < 8; ++j)
                    pp[j] = pldT[w][(st * 32 + q * 8 + j) * 36 + rt * 16 + c];
#pragma unroll
                for (int s2 = 0; s2 < 2; ++s2)
                    acc[rt][s2] = __builtin_amdgcn_mfma_f32_16x16x32_bf16(pf, vf[s2][st], acc[rt][s2], 0, 0, 0);
            }
        }
    }

    // row-sum over the 16 c-lanes of each quad-group
#pragma unroll
    for (int rt = 0; rt < 2; ++rt)
#pragma unroll
        for (int m = 1; m < 16; m <<= 1)
#pragma unroll
            for (int r = 0; r < 4; ++r)
                lsum[rt][r] += __shfl_xor(lsum[rt][r], m);

    // write raw partials
    const long long base = ((long long)(ks * 4 + b)) * NQ;
#pragma unroll
    for (int rt = 0; rt < 2; ++rt) {
#pragma unroll
        for (int r = 0; r < 4; ++r) {
            const int n = nb + rt * 16 + 4 * q + r;
#pragma unroll
            for (int s2 = 0; s2 < 2; ++s2)
                pacc[(base + n) * 32 + s2 * 16 + c] = acc[rt][s2][r];
            if (c == 0) plsum[base + n] = lsum[rt][r];
        }
    }
}

// ---------------------------------------------------------------------------
// Kernel 3: reduce partials, y = sum(acc)/sum(l), out-projection + residual.
// Grid: 576 blocks x 128 thr (2 waves x 32 rows).
// ---------------------------------------------------------------------------
__global__ __launch_bounds__(128) void reduce_kernel(
    const float* __restrict__ pacc, const float* __restrict__ plsum,
    const float* __restrict__ w_out, const float* __restrict__ b_out,
    const float* __restrict__ x, float* __restrict__ out, int nks)
{
    __shared__ unsigned short pld[2][32 * 40];

    const int tid  = threadIdx.x;
    const int w    = tid >> 6;
    const int lane = tid & 63;
    const int q = lane >> 4;
    const int c = lane & 15;

    const int b  = blockIdx.x / 144;
    const int nb = (blockIdx.x % 144) * 64 + w * 32;

    // w_out B-frags: B[k=ci][col=chn] = w_out[chn][ci]
    bf16x8 wof[4];
    float bo[4];
#pragma unroll
    for (int ct = 0; ct < 4; ++ct) {
        const float* wsrc = w_out + (ct * 16 + c) * 32 + q * 8;
        f32x4 w0 = *(const f32x4*)wsrc;
        f32x4 w1 = *(const f32x4*)(wsrc + 4);
        unsigned short* wk = (unsigned short*)&wof[ct];
#pragma unroll
        for (int j = 0; j < 4; ++j) { wk[j] = f2bf(w0[j]); wk[4 + j] = f2bf(w1[j]); }
        bo[ct] = b_out[ct * 16 + c];
    }

    f32x4 acc[2][2];
    f32x4 lsum[2];
#pragma unroll
    for (int rt = 0; rt < 2; ++rt) {
        lsum[rt] = (f32x4){0.f, 0.f, 0.f, 0.f};
#pragma unroll
        for (int s2 = 0; s2 < 2; ++s2) acc[rt][s2] = (f32x4){0.f, 0.f, 0.f, 0.f};
    }
    for (int ks = 0; ks < nks; ++ks) {
        const long long base = ((long long)(ks * 4 + b)) * NQ;
#pragma unroll
        for (int rt = 0; rt < 2; ++rt) {
#pragma unroll
            for (int r = 0; r < 4; ++r) {
                const int n = nb + rt * 16 + 4 * q + r;
#pragma unroll
                for (int s2 = 0; s2 < 2; ++s2)
                    acc[rt][s2][r] += pacc[(base + n) * 32 + s2 * 16 + c];
                lsum[rt][r] += plsum[base + n];
            }
        }
    }

    // y = acc / l -> pld (row-major, stride 40) -> A-frags -> out-proj MFMA
#pragma unroll
    for (int rt = 0; rt < 2; ++rt) {
        f32x4 rv;
#pragma unroll
        for (int r = 0; r < 4; ++r) rv[r] = 1.0f / lsum[rt][r];
#pragma unroll
        for (int s2 = 0; s2 < 2; ++s2)
#pragma unroll
            for (int r = 0; r < 4; ++r)
                pld[w][(rt * 16 + 4 * q + r) * 40 + s2 * 16 + c] = f2bf(acc[rt][s2][r] * rv[r]);
    }
#pragma unroll
    for (int rt = 0; rt < 2; ++rt) {
        bf16x8 yf = *(const bf16x8*)(pld[w] + (rt * 16 + c) * 40 + q * 8);
#pragma unroll
        for (int ct = 0; ct < 4; ++ct) {
            f32x4 z = {0.f, 0.f, 0.f, 0.f};
            f32x4 o = __builtin_amdgcn_mfma_f32_16x16x32_bf16(yf, wof[ct], z, 0, 0, 0);
#pragma unroll
            for (int r = 0; r < 4; ++r) {
                const int n = nb + rt * 16 + 4 * q + r;
                const int addr = (b * 64 + ct * 16 + c) * NQ + n;
                out[addr] = o[r] + bo[ct] + x[addr];
            }
        }
    }
}

extern "C" void kernel_launch(void* const* d_in, const int* in_sizes, int n_in,
                              void* d_out, int out_size, void* d_ws, size_t ws_size,
                              hipStream_t stream) {
    const float* x       = (const float*)d_in[0];
    const float* w_theta = (const float*)d_in[1];
    const float* b_theta = (const float*)d_in[2];
    const float* w_phi   = (const float*)d_in[3];
    const float* b_phi   = (const float*)d_in[4];
    const float* w_g     = (const float*)d_in[5];
    const float* b_g     = (const float*)d_in[6];
    const float* w_out   = (const float*)d_in[7];
    const float* b_out   = (const float*)d_in[8];
    float* out = (float*)d_out;

    // ws layout (bytes):
    //   theta bf16 [4][9216][32]   : 2,359,296
    //   phi   bf16 [4][4608][32]   : 1,179,648
    //   gT    bf16 [4][32][4608]   : 1,179,648
    //   pacc  f32  [KS][4][9216][32]: KS*4,718,592
    //   plsum f32  [KS][4][9216]    : KS*147,456
    const size_t fixed = 2359296 + 1179648 + 1179648;
    int KS = 4;
    while (KS > 1 && fixed + (size_t)KS * (4718592 + 147456) > ws_size) KS >>= 1;

    unsigned short* theta = (unsigned short*)d_ws;
    unsigned short* phi   = theta + 4 * NQ * 32;
    unsigned short* gT    = phi + 4 * MM * 32;
    float* pacc  = (float*)((char*)d_ws + fixed);
    float* plsum = pacc + (size_t)KS * 4 * NQ * 32;

    proj_kernel<<<576, 256, 0, stream>>>(x, w_theta, b_theta, w_phi, b_phi,
                                         w_g, b_g, theta, phi, gT);
    attn_kernel<<<KS * 288, 256, 0, stream>>>(theta, phi, gT, pacc, plsum, 72 / KS);
    reduce_kernel<<<576, 128, 0, stream>>>(pacc, plsum, w_out, b_out, x, out, KS);
}